// Round 6
// baseline (146.123 us; speedup 1.0000x reference)
//
#include <hip/hip_runtime.h>
#include <hip/hip_bf16.h>

typedef __bf16 bf16x8 __attribute__((ext_vector_type(8)));
typedef float f32x4 __attribute__((ext_vector_type(4)));
typedef float f32x16 __attribute__((ext_vector_type(16)));
typedef unsigned short u16;
typedef u16 u16x8 __attribute__((ext_vector_type(8)));

__device__ __forceinline__ u16 f2bf(float f) {
  union { float f; unsigned u; } v; v.f = f;
  unsigned r = v.u + 0x7fffu + ((v.u >> 16) & 1u);
  return (u16)(r >> 16);
}
__device__ __forceinline__ float bf2f(u16 u) {
  union { unsigned u; float f; } v; v.u = (unsigned)u << 16; return v.f;
}
__device__ __forceinline__ unsigned cvtpk(float a, float b) {
  unsigned r;
  asm("v_cvt_pk_bf16_f32 %0, %1, %2" : "=v"(r) : "v"(a), "v"(b));
  return r;
}
__device__ __forceinline__ float exp2_(float x) {
  float r;
  asm("v_exp_f32 %0, %1" : "=v"(r) : "v"(x));
  return r;
}
// async global->LDS, 16B per lane, dest = wave-uniform base + lane*16
__device__ __forceinline__ void gload16(const void* g, void* l) {
  __builtin_amdgcn_global_load_lds(
      (__attribute__((address_space(1))) void*)(void*)g,
      (__attribute__((address_space(3))) void*)l, 16, 0, 0);
}

union U8 { bf16x8 v; unsigned u[4]; };

// ---------------- cast x: f32 -> bf16, 8 elems/thread ----------------
__global__ __launch_bounds__(256) void cast_x_k(const float* __restrict__ x,
                                                u16* __restrict__ xb, int n8) {
  int id = blockIdx.x * 256 + threadIdx.x;
  if (id >= n8) return;
  const float4* p = (const float4*)(x + (size_t)id * 8);
  float4 a = p[0], b = p[1];
  u16x8 o;
  o[0] = f2bf(a.x); o[1] = f2bf(a.y); o[2] = f2bf(a.z); o[3] = f2bf(a.w);
  o[4] = f2bf(b.x); o[5] = f2bf(b.y); o[6] = f2bf(b.z); o[7] = f2bf(b.w);
  *(u16x8*)(xb + (size_t)id * 8) = o;
}

// ------------- transpose-cast W [R][Cc] f32 -> Wt [Cc][R] bf16 -------------
__global__ __launch_bounds__(256) void tcast_k(const float* __restrict__ W,
                                               u16* __restrict__ Wt, int R, int Cc) {
  __shared__ float tile[32][33];
  int bx = blockIdx.x * 32, by = blockIdx.y * 32;
  int tx = threadIdx.x & 31, ty = threadIdx.x >> 5;
#pragma unroll
  for (int j = 0; j < 4; j++)
    tile[ty + j * 8][tx] = W[(size_t)(by + ty + j * 8) * Cc + bx + tx];
  __syncthreads();
#pragma unroll
  for (int j = 0; j < 4; j++)
    Wt[(size_t)(bx + ty + j * 8) * R + by + tx] = f2bf(tile[tx][ty + j * 8]);
}

// ---------------- GEMM: C[M][N] = A[M][K](bf16) * Bt[N][K](bf16) + bias ----------------
template <bool BF16OUT>
__global__ __launch_bounds__(256) void gemm_bt_k(const u16* __restrict__ A,
                                                 const u16* __restrict__ Bt,
                                                 const float* __restrict__ bias,
                                                 void* __restrict__ Cv,
                                                 int M, int N, int K) {
  __shared__ u16 As[128 * 64];
  __shared__ u16 Bs[128 * 64];
  int tid = threadIdx.x;
  int m0 = blockIdx.y * 128, n0 = blockIdx.x * 128;
  int wave = tid >> 6, lane = tid & 63;
  int wm = (wave & 1) * 64, wn = (wave >> 1) * 64;
  int lrow = lane & 15, lk = (lane >> 4) * 8;
  int rr = lane >> 3, cb = (lane & 7) * 16;

  f32x4 acc[4][4] = {};

  for (int k0 = 0; k0 < K; k0 += 64) {
#pragma unroll
    for (int i = 0; i < 4; i++) {
      int row = wave * 32 + i * 8 + rr;
      int cc = (cb ^ ((row & 7) << 4)) >> 1;
      gload16(A + (size_t)(m0 + row) * K + k0 + cc, &As[(wave * 32 + i * 8) * 64]);
      gload16(Bt + (size_t)(n0 + row) * K + k0 + cc, &Bs[(wave * 32 + i * 8) * 64]);
    }
    __syncthreads();
#pragma unroll
    for (int kk = 0; kk < 2; kk++) {
      bf16x8 af[4], bfr[4];
#pragma unroll
      for (int i = 0; i < 4; i++) {
        int arow = wm + i * 16 + lrow;
        int ab = (arow * 128 + (kk * 32 + lk) * 2) ^ ((arow & 7) << 4);
        af[i] = *(const bf16x8*)((const char*)As + ab);
        int brow = wn + i * 16 + lrow;
        int bb = (brow * 128 + (kk * 32 + lk) * 2) ^ ((brow & 7) << 4);
        bfr[i] = *(const bf16x8*)((const char*)Bs + bb);
      }
#pragma unroll
      for (int i = 0; i < 4; i++)
#pragma unroll
        for (int j = 0; j < 4; j++)
          acc[i][j] = __builtin_amdgcn_mfma_f32_16x16x32_bf16(af[i], bfr[j], acc[i][j], 0, 0, 0);
    }
    __syncthreads();
  }
  int rg = lane >> 4;
#pragma unroll
  for (int i = 0; i < 4; i++) {
#pragma unroll
    for (int j = 0; j < 4; j++) {
      int col = n0 + wn + j * 16 + lrow;
      float bz = bias ? bias[col] : 0.f;
#pragma unroll
      for (int r = 0; r < 4; r++) {
        int row = m0 + wm + i * 16 + rg * 4 + r;
        float val = acc[i][j][r] + bz;
        if constexpr (BF16OUT)
          ((u16*)Cv)[(size_t)row * N + col] = f2bf(val);
        else
          ((float*)Cv)[(size_t)row * N + col] = val;
      }
    }
  }
}

// ---------------- RoPE on q,k (bf16 in); Q pre-scaled by 0.125*log2e ----------------
// Both Q and K written FRAGMENT-MAJOR:
// Qf[(bh*64+qt)*2048 + ds*512 + (hi*32+ql)*8 + j]  (qt = 32-row tile)
// Kf[((bh*32+kt)*2+half)*2048 + ds*512 + (hi*32+kl)*8 + j]  (kt = 64-row tile)
__global__ __launch_bounds__(256) void rope_qk_k(const u16* __restrict__ qkv,
                                                 u16* __restrict__ qfb,
                                                 u16* __restrict__ kfb) {
  int id = blockIdx.x * 256 + threadIdx.x;
  int i = id & 31;
  int h = (id >> 5) & 15;
  int t = (id >> 9) & 2047;
  int b = id >> 20;
  size_t row = (size_t)b * 2048 + t;
  const u16* base = qkv + row * 3072 + h * 64 + 2 * i;
  ushort2 qp = *(const ushort2*)(base);
  ushort2 kp = *(const ushort2*)(base + 1024);
  float qx = bf2f(qp.x), qy = bf2f(qp.y), kx = bf2f(kp.x), ky = bf2f(kp.y);
  float freq = exp2f((float)i * -0.41524101186092029f);
  float ang = (float)t * freq;
  float sv, cv;
  sincosf(ang, &sv, &cv);
  const float QS = 0.18033688011112042f;  // 0.125 * log2(e)
  int bh = b * 16 + h;
  ushort2 qo, ko;
  qo.x = f2bf((qx * cv - qy * sv) * QS); qo.y = f2bf((qx * sv + qy * cv) * QS);
  ko.x = f2bf(kx * cv - ky * sv);        ko.y = f2bf(kx * sv + ky * cv);
  int de = 2 * i;
  int ds = de >> 4, hb = (de >> 3) & 1, j = de & 7;
  size_t qidx = ((size_t)bh * 64 + (t >> 5)) * 2048 + ds * 512 + (hb * 32 + (t & 31)) * 8 + j;
  *(ushort2*)(qfb + qidx) = qo;
  size_t kidx = (((size_t)bh * 32 + (t >> 6)) * 2 + ((t >> 5) & 1)) * 2048 +
                ds * 512 + (hb * 32 + (t & 31)) * 8 + j;
  *(ushort2*)(kfb + kidx) = ko;
}

// ---------------- V pack fragment-major ----------------
// Vf[(bh*32+kt)*4096 + dh*2048 + s*512 + (hi*32+ql)*8 + j] = V[bh][kt*64+s*16+hi*8+j][dh*32+ql]
__global__ __launch_bounds__(256) void v_pack_k(const u16* __restrict__ qkv,
                                                u16* __restrict__ vf) {
  __shared__ u16 tl[64][72];
  int bh = blockIdx.x, kt = blockIdx.y;
  int b = bh >> 4, h = bh & 15;
  int tid = threadIdx.x;
#pragma unroll
  for (int rep = 0; rep < 2; rep++) {
    int tr = rep * 32 + (tid >> 3);
    int dc = (tid & 7) * 8;
    u16x8 v = *(const u16x8*)(qkv + ((size_t)(b * 2048 + kt * 64 + tr)) * 3072 + 2048 + h * 64 + dc);
    *(u16x8*)&tl[tr][dc] = v;
  }
  __syncthreads();
  u16* dst = vf + ((size_t)bh * 32 + kt) * 4096;
#pragma unroll
  for (int rep = 0; rep < 2; rep++) {
    int c = rep * 256 + tid;
    int dh = c >> 8, s = (c >> 6) & 3, l = c & 63;
    int hi = l >> 5, ql = l & 31;
    u16x8 o;
#pragma unroll
    for (int j = 0; j < 8; j++) o[j] = tl[s * 16 + hi * 8 + j][dh * 32 + ql];
    *(u16x8*)(dst + (size_t)c * 8) = o;
  }
}

// ---------------- flash attention v6: 2 waves split KV by parity + merge ----------------
// 1024 blocks x 2 waves. Block = pair {qt=p, 63-p} for one bh (uniform 33 tiles).
// Each wave does alternating KV tiles (parity flipped per phase); per-phase
// online-softmax merge through LDS. 2048 waves -> 2/SIMD resident.

#define ATT_PREF(Pa, Pb, IT)                                                      \
  do {                                                                            \
    const u16* kb_ = KfP + (size_t)(IT) * 4096 + ln8;                             \
    _Pragma("unroll") for (int d_ = 0; d_ < 4; d_++) {                            \
      Pa[d_] = *(const bf16x8*)(kb_ + d_ * 512);                                  \
      Pb[d_] = *(const bf16x8*)(kb_ + 2048 + d_ * 512);                           \
    }                                                                             \
  } while (0)

#define ATT_BODY(Pa, Pb, IT)                                                      \
  do {                                                                            \
    int kv0_ = (IT) * 64;                                                         \
    const u16* vb_ = VfP + (size_t)(IT) * 4096 + ln8;                             \
    f32x16 sa = {}, sb = {};                                                      \
    _Pragma("unroll") for (int d_ = 0; d_ < 4; d_++) {                            \
      sa = __builtin_amdgcn_mfma_f32_32x32x16_bf16(Pa[d_], qf[d_], sa, 0, 0, 0);  \
      sb = __builtin_amdgcn_mfma_f32_32x32x16_bf16(Pb[d_], qf[d_], sb, 0, 0, 0);  \
    }                                                                             \
    bf16x8 v0_[4], v1_[4];                                                        \
    _Pragma("unroll") for (int s_ = 0; s_ < 4; s_++) {                            \
      v0_[s_] = *(const bf16x8*)(vb_ + s_ * 512);                                 \
      v1_[s_] = *(const bf16x8*)(vb_ + 2048 + s_ * 512);                          \
    }                                                                             \
    if ((IT) == nIter - 1) {                                                      \
      _Pragma("unroll") for (int r_ = 0; r_ < 16; r_++) {                         \
        int ro_ = (r_ & 3) + 8 * (r_ >> 2) + 4 * hi;                              \
        if (kv0_ + ro_ > qg) sa[r_] = -3e38f;                                     \
        if (kv0_ + 32 + ro_ > qg) sb[r_] = -3e38f;                                \
      }                                                                           \
    }                                                                             \
    float ta_ = -3e38f, tb_ = -3e38f;                                             \
    _Pragma("unroll") for (int r_ = 0; r_ < 8; r_++) {                            \
      ta_ = fmaxf(ta_, fmaxf(sa[r_], sa[r_ + 8]));                                \
      tb_ = fmaxf(tb_, fmaxf(sb[r_], sb[r_ + 8]));                                \
    }                                                                             \
    float tmax_ = fmaxf(ta_, tb_);                                                \
    tmax_ = fmaxf(tmax_, __shfl_xor(tmax_, 32));                                  \
    if (!__all(tmax_ <= m + 11.5409f)) {                                          \
      float mn_ = fmaxf(m, tmax_);                                                \
      float corr_ = exp2_(m - mn_);                                               \
      m = mn_;                                                                    \
      ls[0] *= corr_;                                                             \
      _Pragma("unroll") for (int r_ = 0; r_ < 16; r_++) {                         \
        o0[r_] *= corr_; o1[r_] *= corr_;                                         \
      }                                                                           \
    }                                                                             \
    _Pragma("unroll") for (int r_ = 0; r_ < 16; r_++) {                           \
      sa[r_] = exp2_(sa[r_] - m);                                                 \
      sb[r_] = exp2_(sb[r_] - m);                                                 \
    }                                                                             \
    unsigned wA_[8], xA_[8], wB_[8], xB_[8];                                      \
    _Pragma("unroll") for (int j_ = 0; j_ < 8; j_++) {                            \
      wA_[j_] = cvtpk(sa[2 * j_], sa[2 * j_ + 1]);                                \
      wB_[j_] = cvtpk(sb[2 * j_], sb[2 * j_ + 1]);                                \
    }                                                                             \
    _Pragma("unroll") for (int j_ = 0; j_ < 8; j_++) {                            \
      xA_[j_] = (unsigned)__shfl_xor((int)wA_[j_], 32);                           \
      xB_[j_] = (unsigned)__shfl_xor((int)wB_[j_], 32);                           \
    }                                                                             \
    U8 pf0_, pf1_, pf2_, pf3_;                                                    \
    pf0_.u[0] = hi ? xA_[2] : wA_[0]; pf0_.u[1] = hi ? xA_[3] : wA_[1];           \
    pf0_.u[2] = hi ? wA_[2] : xA_[0]; pf0_.u[3] = hi ? wA_[3] : xA_[1];           \
    pf1_.u[0] = hi ? xA_[6] : wA_[4]; pf1_.u[1] = hi ? xA_[7] : wA_[5];           \
    pf1_.u[2] = hi ? wA_[6] : xA_[4]; pf1_.u[3] = hi ? wA_[7] : xA_[5];           \
    pf2_.u[0] = hi ? xB_[2] : wB_[0]; pf2_.u[1] = hi ? xB_[3] : wB_[1];           \
    pf2_.u[2] = hi ? wB_[2] : xB_[0]; pf2_.u[3] = hi ? wB_[3] : xB_[1];           \
    pf3_.u[0] = hi ? xB_[6] : wB_[4]; pf3_.u[1] = hi ? xB_[7] : wB_[5];           \
    pf3_.u[2] = hi ? wB_[6] : xB_[4]; pf3_.u[3] = hi ? wB_[7] : xB_[5];           \
    o0 = __builtin_amdgcn_mfma_f32_32x32x16_bf16(v0_[0], pf0_.v, o0, 0, 0, 0);    \
    o1 = __builtin_amdgcn_mfma_f32_32x32x16_bf16(v1_[0], pf0_.v, o1, 0, 0, 0);    \
    o0 = __builtin_amdgcn_mfma_f32_32x32x16_bf16(v0_[1], pf1_.v, o0, 0, 0, 0);    \
    o1 = __builtin_amdgcn_mfma_f32_32x32x16_bf16(v1_[1], pf1_.v, o1, 0, 0, 0);    \
    o0 = __builtin_amdgcn_mfma_f32_32x32x16_bf16(v0_[2], pf2_.v, o0, 0, 0, 0);    \
    o1 = __builtin_amdgcn_mfma_f32_32x32x16_bf16(v1_[2], pf2_.v, o1, 0, 0, 0);    \
    o0 = __builtin_amdgcn_mfma_f32_32x32x16_bf16(v0_[3], pf3_.v, o0, 0, 0, 0);    \
    o1 = __builtin_amdgcn_mfma_f32_32x32x16_bf16(v1_[3], pf3_.v, o1, 0, 0, 0);    \
    ls = __builtin_amdgcn_mfma_f32_32x32x16_bf16(onesf.v, pf0_.v, ls, 0, 0, 0);   \
    ls = __builtin_amdgcn_mfma_f32_32x32x16_bf16(onesf.v, pf1_.v, ls, 0, 0, 0);   \
    ls = __builtin_amdgcn_mfma_f32_32x32x16_bf16(onesf.v, pf2_.v, ls, 0, 0, 0);   \
    ls = __builtin_amdgcn_mfma_f32_32x32x16_bf16(onesf.v, pf3_.v, ls, 0, 0, 0);   \
  } while (0)

__global__ __launch_bounds__(128) void attn_k(const u16* __restrict__ Qf,
                                              const u16* __restrict__ Kf,
                                              const u16* __restrict__ Vf,
                                              u16* __restrict__ Os) {
  __shared__ float smO[64][33];
  __shared__ float smM[64], smL[64];
  const int T = 2048;
  int blk = blockIdx.x;
  int g = blk & 7;                 // XCD group
  int bh = g * 4 + ((blk >> 3) & 3);
  int p = blk >> 5;                // 0..31
  int wave = threadIdx.x >> 6;
  int lane = threadIdx.x & 63;
  int ql = lane & 31, hi = lane >> 5;
  int ln8 = lane * 8;
  const u16* QfP = Qf + (size_t)bh * 64 * 2048;
  const u16* KfP = Kf + (size_t)bh * 32 * 4096;
  const u16* VfP = Vf + (size_t)bh * 32 * 4096;
  int b = bh >> 4, h = bh & 15;

  U8 onesf;
#pragma unroll
  for (int j = 0; j < 4; j++) onesf.u[j] = 0x3F803F80u;

#pragma unroll 1
  for (int ph = 0; ph < 2; ph++) {
    const int qt = ph ? 63 - p : p;
    const int qg = qt * 32 + ql;
    const int nIter = (qt >> 1) + 1;
    const int par = wave ^ ph;  // flip parity per phase to balance counts

    bf16x8 qf[4];
#pragma unroll
    for (int ds = 0; ds < 4; ds++)
      qf[ds] = *(const bf16x8*)(QfP + (size_t)qt * 2048 + ds * 512 + ln8);

    f32x16 o0 = {}, o1 = {}, ls = {};
    float m = -1e30f;

    bf16x8 Aa[4], Ab[4], Ba[4], Bb[4];
    int it = par;
    if (it < nIter) {
      ATT_PREF(Aa, Ab, it);
      while (true) {
        if (it + 2 < nIter) ATT_PREF(Ba, Bb, it + 2);
        ATT_BODY(Aa, Ab, it);
        it += 2;
        if (it >= nIter) break;
        if (it + 2 < nIter) ATT_PREF(Aa, Ab, it + 2);
        ATT_BODY(Ba, Bb, it);
        it += 2;
        if (it >= nIter) break;
      }
    }

    // ---- cross-wave online-softmax merge (exact for partial triples) ----
    if (wave == 1) {
#pragma unroll
      for (int r = 0; r < 16; r++) {
        smO[lane][r] = o0[r];
        smO[lane][16 + r] = o1[r];
      }
      smM[lane] = m;
      smL[lane] = ls[0];
    }
    __syncthreads();
    if (wave == 0) {
      float m1 = smM[lane], l1 = smL[lane];
      float mt = fmaxf(m, m1);
      float a0 = exp2_(m - mt), a1 = exp2_(m1 - mt);
      float lt = ls[0] * a0 + l1 * a1;
      float inv = 1.f / lt;
      float c0 = a0 * inv, c1 = a1 * inv;
      u16* orow = Os + ((size_t)(b * T + qg)) * 1024 + h * 64;
#pragma unroll
      for (int j = 0; j < 4; j++) {
        ushort4 o;
        o.x = f2bf(o0[4 * j + 0] * c0 + smO[lane][4 * j + 0] * c1);
        o.y = f2bf(o0[4 * j + 1] * c0 + smO[lane][4 * j + 1] * c1);
        o.z = f2bf(o0[4 * j + 2] * c0 + smO[lane][4 * j + 2] * c1);
        o.w = f2bf(o0[4 * j + 3] * c0 + smO[lane][4 * j + 3] * c1);
        *(ushort4*)(orow + 8 * j + 4 * hi) = o;
        ushort4 q2;
        q2.x = f2bf(o1[4 * j + 0] * c0 + smO[lane][16 + 4 * j + 0] * c1);
        q2.y = f2bf(o1[4 * j + 1] * c0 + smO[lane][16 + 4 * j + 1] * c1);
        q2.z = f2bf(o1[4 * j + 2] * c0 + smO[lane][16 + 4 * j + 2] * c1);
        q2.w = f2bf(o1[4 * j + 3] * c0 + smO[lane][16 + 4 * j + 3] * c1);
        *(ushort4*)(orow + 32 + 8 * j + 4 * hi) = q2;
      }
    }
    __syncthreads();
  }
}

extern "C" void kernel_launch(void* const* d_in, const int* in_sizes, int n_in,
                              void* d_out, int out_size, void* d_ws, size_t ws_size,
                              hipStream_t stream) {
  const float* x      = (const float*)d_in[0];
  const float* W_qkv  = (const float*)d_in[1];
  const float* b_qkv  = (const float*)d_in[2];
  const float* W_proj = (const float*)d_in[3];
  const float* b_proj = (const float*)d_in[4];
  float* out = (float*)d_out;

  const int B = 2, T = 2048, C = 1024;
  const int M = B * T;  // 4096

  char* ws = (char*)d_ws;
  u16* xb     = (u16*)(ws);                       // 8 MB
  u16* wqkvt  = (u16*)(ws + (8ull << 20));        // 6 MB
  u16* wprojt = (u16*)(ws + (14ull << 20));       // 2 MB
  u16* qfb    = (u16*)(ws + (16ull << 20));       // 8 MB (fragment-major Q)
  u16* kfb    = (u16*)(ws + (24ull << 20));       // 8 MB (fragment-major K)
  u16* vfb    = (u16*)(ws + (32ull << 20));       // 8 MB (fragment-major V)
  u16* sc     = (u16*)(ws + (40ull << 20));       // 8 MB
  u16* qkvb   = (u16*)(ws + (48ull << 20));       // 24 MB (bf16 qkv)

  cast_x_k<<<(M * C / 8 + 255) / 256, 256, 0, stream>>>(x, xb, M * C / 8);
  tcast_k<<<dim3(3 * C / 32, C / 32), 256, 0, stream>>>(W_qkv, wqkvt, C, 3 * C);
  tcast_k<<<dim3(C / 32, C / 32), 256, 0, stream>>>(W_proj, wprojt, C, C);
  gemm_bt_k<true><<<dim3(3 * C / 128, M / 128), 256, 0, stream>>>(xb, wqkvt, b_qkv, qkvb, M, 3 * C, C);
  rope_qk_k<<<(B * T * 16 * 32) / 256, 256, 0, stream>>>(qkvb, qfb, kfb);
  v_pack_k<<<dim3(B * 16, T / 64), 256, 0, stream>>>(qkvb, vfb);
  attn_k<<<1024, 128, 0, stream>>>(qfb, kfb, vfb, sc);
  gemm_bt_k<false><<<dim3(C / 128, M / 128), 256, 0, stream>>>(sc, wprojt, b_proj, out, M, C, C);
}

// Round 7
// 139.014 us; speedup vs baseline: 1.0511x; 1.0511x over previous
//
#include <hip/hip_runtime.h>
#include <hip/hip_bf16.h>

typedef __bf16 bf16x8 __attribute__((ext_vector_type(8)));
typedef float f32x4 __attribute__((ext_vector_type(4)));
typedef float f32x16 __attribute__((ext_vector_type(16)));
typedef unsigned short u16;
typedef u16 u16x8 __attribute__((ext_vector_type(8)));

__device__ __forceinline__ u16 f2bf(float f) {
  union { float f; unsigned u; } v; v.f = f;
  unsigned r = v.u + 0x7fffu + ((v.u >> 16) & 1u);
  return (u16)(r >> 16);
}
__device__ __forceinline__ float bf2f(u16 u) {
  union { unsigned u; float f; } v; v.u = (unsigned)u << 16; return v.f;
}
__device__ __forceinline__ unsigned cvtpk(float a, float b) {
  unsigned r;
  asm("v_cvt_pk_bf16_f32 %0, %1, %2" : "=v"(r) : "v"(a), "v"(b));
  return r;
}
__device__ __forceinline__ float exp2_(float x) {
  float r;
  asm("v_exp_f32 %0, %1" : "=v"(r) : "v"(x));
  return r;
}
// async global->LDS, 16B per lane, dest = wave-uniform base + lane*16
__device__ __forceinline__ void gload16(const void* g, void* l) {
  __builtin_amdgcn_global_load_lds(
      (__attribute__((address_space(1))) void*)(void*)g,
      (__attribute__((address_space(3))) void*)l, 16, 0, 0);
}

union U8 { bf16x8 v; unsigned u[4]; };

// ---------------- cast x: f32 -> bf16, 8 elems/thread ----------------
__global__ __launch_bounds__(256) void cast_x_k(const float* __restrict__ x,
                                                u16* __restrict__ xb, int n8) {
  int id = blockIdx.x * 256 + threadIdx.x;
  if (id >= n8) return;
  const float4* p = (const float4*)(x + (size_t)id * 8);
  float4 a = p[0], b = p[1];
  u16x8 o;
  o[0] = f2bf(a.x); o[1] = f2bf(a.y); o[2] = f2bf(a.z); o[3] = f2bf(a.w);
  o[4] = f2bf(b.x); o[5] = f2bf(b.y); o[6] = f2bf(b.z); o[7] = f2bf(b.w);
  *(u16x8*)(xb + (size_t)id * 8) = o;
}

// ------------- transpose-cast W [R][Cc] f32 -> Wt [Cc][R] bf16 -------------
__global__ __launch_bounds__(256) void tcast_k(const float* __restrict__ W,
                                               u16* __restrict__ Wt, int R, int Cc) {
  __shared__ float tile[32][33];
  int bx = blockIdx.x * 32, by = blockIdx.y * 32;
  int tx = threadIdx.x & 31, ty = threadIdx.x >> 5;
#pragma unroll
  for (int j = 0; j < 4; j++)
    tile[ty + j * 8][tx] = W[(size_t)(by + ty + j * 8) * Cc + bx + tx];
  __syncthreads();
#pragma unroll
  for (int j = 0; j < 4; j++)
    Wt[(size_t)(bx + ty + j * 8) * R + by + tx] = f2bf(tile[tx][ty + j * 8]);
}

// ---------------- GEMM: C[M][N] = A[M][K](bf16) * Bt[N][K](bf16) + bias ----------------
template <bool BF16OUT>
__global__ __launch_bounds__(256) void gemm_bt_k(const u16* __restrict__ A,
                                                 const u16* __restrict__ Bt,
                                                 const float* __restrict__ bias,
                                                 void* __restrict__ Cv,
                                                 int M, int N, int K) {
  __shared__ u16 As[128 * 64];
  __shared__ u16 Bs[128 * 64];
  int tid = threadIdx.x;
  int m0 = blockIdx.y * 128, n0 = blockIdx.x * 128;
  int wave = tid >> 6, lane = tid & 63;
  int wm = (wave & 1) * 64, wn = (wave >> 1) * 64;
  int lrow = lane & 15, lk = (lane >> 4) * 8;
  int rr = lane >> 3, cb = (lane & 7) * 16;

  f32x4 acc[4][4] = {};

  for (int k0 = 0; k0 < K; k0 += 64) {
#pragma unroll
    for (int i = 0; i < 4; i++) {
      int row = wave * 32 + i * 8 + rr;
      int cc = (cb ^ ((row & 7) << 4)) >> 1;
      gload16(A + (size_t)(m0 + row) * K + k0 + cc, &As[(wave * 32 + i * 8) * 64]);
      gload16(Bt + (size_t)(n0 + row) * K + k0 + cc, &Bs[(wave * 32 + i * 8) * 64]);
    }
    __syncthreads();
#pragma unroll
    for (int kk = 0; kk < 2; kk++) {
      bf16x8 af[4], bfr[4];
#pragma unroll
      for (int i = 0; i < 4; i++) {
        int arow = wm + i * 16 + lrow;
        int ab = (arow * 128 + (kk * 32 + lk) * 2) ^ ((arow & 7) << 4);
        af[i] = *(const bf16x8*)((const char*)As + ab);
        int brow = wn + i * 16 + lrow;
        int bb = (brow * 128 + (kk * 32 + lk) * 2) ^ ((brow & 7) << 4);
        bfr[i] = *(const bf16x8*)((const char*)Bs + bb);
      }
#pragma unroll
      for (int i = 0; i < 4; i++)
#pragma unroll
        for (int j = 0; j < 4; j++)
          acc[i][j] = __builtin_amdgcn_mfma_f32_16x16x32_bf16(af[i], bfr[j], acc[i][j], 0, 0, 0);
    }
    __syncthreads();
  }
  int rg = lane >> 4;
#pragma unroll
  for (int i = 0; i < 4; i++) {
#pragma unroll
    for (int j = 0; j < 4; j++) {
      int col = n0 + wn + j * 16 + lrow;
      float bz = bias ? bias[col] : 0.f;
#pragma unroll
      for (int r = 0; r < 4; r++) {
        int row = m0 + wm + i * 16 + rg * 4 + r;
        float val = acc[i][j][r] + bz;
        if constexpr (BF16OUT)
          ((u16*)Cv)[(size_t)row * N + col] = f2bf(val);
        else
          ((float*)Cv)[(size_t)row * N + col] = val;
      }
    }
  }
}

// ---------------- RoPE on q,k (bf16 in); Q pre-scaled by 0.125*log2e ----------------
// Both Q and K written FRAGMENT-MAJOR:
// Qf[(bh*64+qt)*2048 + ds*512 + (hi*32+ql)*8 + j]  (qt = 32-row tile)
// Kf[((bh*32+kt)*2+half)*2048 + ds*512 + (hi*32+kl)*8 + j]  (kt = 64-row tile)
__global__ __launch_bounds__(256) void rope_qk_k(const u16* __restrict__ qkv,
                                                 u16* __restrict__ qfb,
                                                 u16* __restrict__ kfb) {
  int id = blockIdx.x * 256 + threadIdx.x;
  int i = id & 31;
  int h = (id >> 5) & 15;
  int t = (id >> 9) & 2047;
  int b = id >> 20;
  size_t row = (size_t)b * 2048 + t;
  const u16* base = qkv + row * 3072 + h * 64 + 2 * i;
  ushort2 qp = *(const ushort2*)(base);
  ushort2 kp = *(const ushort2*)(base + 1024);
  float qx = bf2f(qp.x), qy = bf2f(qp.y), kx = bf2f(kp.x), ky = bf2f(kp.y);
  float freq = exp2f((float)i * -0.41524101186092029f);
  float ang = (float)t * freq;
  float sv, cv;
  sincosf(ang, &sv, &cv);
  const float QS = 0.18033688011112042f;  // 0.125 * log2(e)
  int bh = b * 16 + h;
  ushort2 qo, ko;
  qo.x = f2bf((qx * cv - qy * sv) * QS); qo.y = f2bf((qx * sv + qy * cv) * QS);
  ko.x = f2bf(kx * cv - ky * sv);        ko.y = f2bf(kx * sv + ky * cv);
  int de = 2 * i;
  int ds = de >> 4, hb = (de >> 3) & 1, j = de & 7;
  size_t qidx = ((size_t)bh * 64 + (t >> 5)) * 2048 + ds * 512 + (hb * 32 + (t & 31)) * 8 + j;
  *(ushort2*)(qfb + qidx) = qo;
  size_t kidx = (((size_t)bh * 32 + (t >> 6)) * 2 + ((t >> 5) & 1)) * 2048 +
                ds * 512 + (hb * 32 + (t & 31)) * 8 + j;
  *(ushort2*)(kfb + kidx) = ko;
}

// ---------------- V pack fragment-major ----------------
// Vf[(bh*32+kt)*4096 + dh*2048 + s*512 + (hi*32+ql)*8 + j] = V[bh][kt*64+s*16+hi*8+j][dh*32+ql]
__global__ __launch_bounds__(256) void v_pack_k(const u16* __restrict__ qkv,
                                                u16* __restrict__ vf) {
  __shared__ u16 tl[64][72];
  int bh = blockIdx.x, kt = blockIdx.y;
  int b = bh >> 4, h = bh & 15;
  int tid = threadIdx.x;
#pragma unroll
  for (int rep = 0; rep < 2; rep++) {
    int tr = rep * 32 + (tid >> 3);
    int dc = (tid & 7) * 8;
    u16x8 v = *(const u16x8*)(qkv + ((size_t)(b * 2048 + kt * 64 + tr)) * 3072 + 2048 + h * 64 + dc);
    *(u16x8*)&tl[tr][dc] = v;
  }
  __syncthreads();
  u16* dst = vf + ((size_t)bh * 32 + kt) * 4096;
#pragma unroll
  for (int rep = 0; rep < 2; rep++) {
    int c = rep * 256 + tid;
    int dh = c >> 8, s = (c >> 6) & 3, l = c & 63;
    int hi = l >> 5, ql = l & 31;
    u16x8 o;
#pragma unroll
    for (int j = 0; j < 8; j++) o[j] = tl[s * 16 + hi * 8 + j][dh * 32 + ql];
    *(u16x8*)(dst + (size_t)c * 8) = o;
  }
}

// ---------------- flash attention v7: QK-ahead pipeline, permlane pack ----------------
// 2048 independent single-wave jobs (one qt each), longest-first dispatch.
// Body t: issue V(t) loads + K(t+2) prefetch + QK(t+1) MFMAs, THEN softmax(t)+PV(t):
// the next tile's QK chain overlaps this tile's VALU softmax (separate pipes).

#define KPREF(K0, K1, IT)                                                         \
  do {                                                                            \
    const u16* kb_ = KfP + (size_t)(IT) * 4096 + ln8;                             \
    _Pragma("unroll") for (int d_ = 0; d_ < 4; d_++) {                            \
      K0[d_] = *(const bf16x8*)(kb_ + d_ * 512);                                  \
      K1[d_] = *(const bf16x8*)(kb_ + 2048 + d_ * 512);                           \
    }                                                                             \
  } while (0)

#define QKC(SA, SB, K0, K1)                                                       \
  do {                                                                            \
    SA = (f32x16){};                                                              \
    SB = (f32x16){};                                                              \
    _Pragma("unroll") for (int d_ = 0; d_ < 4; d_++) {                            \
      SA = __builtin_amdgcn_mfma_f32_32x32x16_bf16(K0[d_], qf[d_], SA, 0, 0, 0);  \
      SB = __builtin_amdgcn_mfma_f32_32x32x16_bf16(K1[d_], qf[d_], SB, 0, 0, 0);  \
    }                                                                             \
  } while (0)

#define VLOADM(IT)                                                                \
  do {                                                                            \
    const u16* vb_ = VfP + (size_t)(IT) * 4096 + ln8;                             \
    _Pragma("unroll") for (int s_ = 0; s_ < 4; s_++) {                            \
      vv0[s_] = *(const bf16x8*)(vb_ + s_ * 512);                                 \
      vv1[s_] = *(const bf16x8*)(vb_ + 2048 + s_ * 512);                          \
    }                                                                             \
  } while (0)

#define SMPV(SA, SB, IT, LASTF)                                                   \
  do {                                                                            \
    if (LASTF) {                                                                  \
      int kv0_ = (IT) * 64;                                                       \
      _Pragma("unroll") for (int r_ = 0; r_ < 16; r_++) {                         \
        int ro_ = (r_ & 3) + 8 * (r_ >> 2) + 4 * hi;                              \
        if (kv0_ + ro_ > qg) SA[r_] = -3e38f;                                     \
        if (kv0_ + 32 + ro_ > qg) SB[r_] = -3e38f;                                \
      }                                                                           \
    }                                                                             \
    float ta_ = -3e38f, tb_ = -3e38f;                                             \
    _Pragma("unroll") for (int r_ = 0; r_ < 8; r_++) {                            \
      ta_ = fmaxf(ta_, fmaxf(SA[r_], SA[r_ + 8]));                                \
      tb_ = fmaxf(tb_, fmaxf(SB[r_], SB[r_ + 8]));                                \
    }                                                                             \
    float tmax_ = fmaxf(ta_, tb_);                                                \
    tmax_ = fmaxf(tmax_, __shfl_xor(tmax_, 32));                                  \
    if (!__all(tmax_ <= m + 11.5409f)) {                                          \
      float mn_ = fmaxf(m, tmax_);                                                \
      float corr_ = exp2_(m - mn_);                                               \
      m = mn_;                                                                    \
      ls[0] *= corr_;                                                             \
      _Pragma("unroll") for (int r_ = 0; r_ < 16; r_++) {                         \
        o0[r_] *= corr_; o1[r_] *= corr_;                                         \
      }                                                                           \
    }                                                                             \
    _Pragma("unroll") for (int r_ = 0; r_ < 16; r_++) {                           \
      SA[r_] = exp2_(SA[r_] - m);                                                 \
      SB[r_] = exp2_(SB[r_] - m);                                                 \
    }                                                                             \
    unsigned w0_ = cvtpk(SA[0], SA[1]),   w1_ = cvtpk(SA[2], SA[3]);              \
    unsigned w2_ = cvtpk(SA[4], SA[5]),   w3_ = cvtpk(SA[6], SA[7]);              \
    unsigned w4_ = cvtpk(SA[8], SA[9]),   w5_ = cvtpk(SA[10], SA[11]);            \
    unsigned w6_ = cvtpk(SA[12], SA[13]), w7_ = cvtpk(SA[14], SA[15]);            \
    unsigned y0_ = cvtpk(SB[0], SB[1]),   y1_ = cvtpk(SB[2], SB[3]);              \
    unsigned y2_ = cvtpk(SB[4], SB[5]),   y3_ = cvtpk(SB[6], SB[7]);              \
    unsigned y4_ = cvtpk(SB[8], SB[9]),   y5_ = cvtpk(SB[10], SB[11]);            \
    unsigned y6_ = cvtpk(SB[12], SB[13]), y7_ = cvtpk(SB[14], SB[15]);            \
    asm("v_permlane32_swap_b32 %0, %1" : "+v"(w0_), "+v"(w2_));                   \
    asm("v_permlane32_swap_b32 %0, %1" : "+v"(w1_), "+v"(w3_));                   \
    asm("v_permlane32_swap_b32 %0, %1" : "+v"(w4_), "+v"(w6_));                   \
    asm("v_permlane32_swap_b32 %0, %1" : "+v"(w5_), "+v"(w7_));                   \
    asm("v_permlane32_swap_b32 %0, %1" : "+v"(y0_), "+v"(y2_));                   \
    asm("v_permlane32_swap_b32 %0, %1" : "+v"(y1_), "+v"(y3_));                   \
    asm("v_permlane32_swap_b32 %0, %1" : "+v"(y4_), "+v"(y6_));                   \
    asm("v_permlane32_swap_b32 %0, %1" : "+v"(y5_), "+v"(y7_));                   \
    U8 pf0_, pf1_, pf2_, pf3_;                                                    \
    pf0_.u[0] = w0_; pf0_.u[1] = w1_; pf0_.u[2] = w2_; pf0_.u[3] = w3_;           \
    pf1_.u[0] = w4_; pf1_.u[1] = w5_; pf1_.u[2] = w6_; pf1_.u[3] = w7_;           \
    pf2_.u[0] = y0_; pf2_.u[1] = y1_; pf2_.u[2] = y2_; pf2_.u[3] = y3_;           \
    pf3_.u[0] = y4_; pf3_.u[1] = y5_; pf3_.u[2] = y6_; pf3_.u[3] = y7_;           \
    o0 = __builtin_amdgcn_mfma_f32_32x32x16_bf16(vv0[0], pf0_.v, o0, 0, 0, 0);    \
    o1 = __builtin_amdgcn_mfma_f32_32x32x16_bf16(vv1[0], pf0_.v, o1, 0, 0, 0);    \
    o0 = __builtin_amdgcn_mfma_f32_32x32x16_bf16(vv0[1], pf1_.v, o0, 0, 0, 0);    \
    o1 = __builtin_amdgcn_mfma_f32_32x32x16_bf16(vv1[1], pf1_.v, o1, 0, 0, 0);    \
    o0 = __builtin_amdgcn_mfma_f32_32x32x16_bf16(vv0[2], pf2_.v, o0, 0, 0, 0);    \
    o1 = __builtin_amdgcn_mfma_f32_32x32x16_bf16(vv1[2], pf2_.v, o1, 0, 0, 0);    \
    o0 = __builtin_amdgcn_mfma_f32_32x32x16_bf16(vv0[3], pf3_.v, o0, 0, 0, 0);    \
    o1 = __builtin_amdgcn_mfma_f32_32x32x16_bf16(vv1[3], pf3_.v, o1, 0, 0, 0);    \
    ls = __builtin_amdgcn_mfma_f32_32x32x16_bf16(onesf.v, pf0_.v, ls, 0, 0, 0);   \
    ls = __builtin_amdgcn_mfma_f32_32x32x16_bf16(onesf.v, pf1_.v, ls, 0, 0, 0);   \
    ls = __builtin_amdgcn_mfma_f32_32x32x16_bf16(onesf.v, pf2_.v, ls, 0, 0, 0);   \
    ls = __builtin_amdgcn_mfma_f32_32x32x16_bf16(onesf.v, pf3_.v, ls, 0, 0, 0);   \
  } while (0)

__global__ __launch_bounds__(64) void attn_k(const u16* __restrict__ Qf,
                                             const u16* __restrict__ Kf,
                                             const u16* __restrict__ Vf,
                                             u16* __restrict__ Os) {
  const int T = 2048;
  int blk = blockIdx.x;
  int g = blk & 7;                       // XCD group (bh locality)
  int bh = g * 4 + ((blk >> 3) & 3);
  int qt = 63 - (blk >> 5);              // longest jobs dispatch first
  int lane = threadIdx.x & 63;
  int ql = lane & 31, hi = lane >> 5;
  int ln8 = lane * 8;
  int qg = qt * 32 + ql;
  int nIter = (qt >> 1) + 1;
  const u16* QfP = Qf + (size_t)bh * 64 * 2048;
  const u16* KfP = Kf + (size_t)bh * 32 * 4096;
  const u16* VfP = Vf + (size_t)bh * 32 * 4096;
  int b = bh >> 4, h = bh & 15;

  U8 onesf;
#pragma unroll
  for (int j = 0; j < 4; j++) onesf.u[j] = 0x3F803F80u;

  bf16x8 qf[4];
#pragma unroll
  for (int ds = 0; ds < 4; ds++)
    qf[ds] = *(const bf16x8*)(QfP + (size_t)qt * 2048 + ds * 512 + ln8);

  f32x16 o0 = {}, o1 = {}, ls = {};
  float m = -1e30f;

  bf16x8 Ka0[4], Ka1[4], Kb0[4], Kb1[4], vv0[4], vv1[4];
  f32x16 sA0, sA1, sB0, sB1;

  KPREF(Ka0, Ka1, 0);
  QKC(sA0, sA1, Ka0, Ka1);               // scores(0)
  if (nIter > 1) KPREF(Kb0, Kb1, 1);

  int t = 0;
  for (;;) {
    bool last = (t == nIter - 1);
    VLOADM(t);
    if (t + 2 < nIter) KPREF(Ka0, Ka1, t + 2);
    if (!last) QKC(sB0, sB1, Kb0, Kb1);  // scores(t+1) overlaps softmax(t)
    SMPV(sA0, sA1, t, last);
    if (last) break;
    ++t;
    last = (t == nIter - 1);
    VLOADM(t);
    if (t + 2 < nIter) KPREF(Kb0, Kb1, t + 2);
    if (!last) QKC(sA0, sA1, Ka0, Ka1);
    SMPV(sB0, sB1, t, last);
    if (last) break;
    ++t;
  }

  // ---- epilogue: O = O^T/l, fused head re-interleave into (B*T, C) bf16 ----
  float inv = 1.f / ls[0];
  u16* orow = Os + ((size_t)(b * T + qg)) * 1024 + h * 64;
#pragma unroll
  for (int j = 0; j < 4; j++) {
    ushort4 o;
    o.x = f2bf(o0[4 * j + 0] * inv); o.y = f2bf(o0[4 * j + 1] * inv);
    o.z = f2bf(o0[4 * j + 2] * inv); o.w = f2bf(o0[4 * j + 3] * inv);
    *(ushort4*)(orow + 8 * j + 4 * hi) = o;
    ushort4 q2;
    q2.x = f2bf(o1[4 * j + 0] * inv); q2.y = f2bf(o1[4 * j + 1] * inv);
    q2.z = f2bf(o1[4 * j + 2] * inv); q2.w = f2bf(o1[4 * j + 3] * inv);
    *(ushort4*)(orow + 32 + 8 * j + 4 * hi) = q2;
  }
}

extern "C" void kernel_launch(void* const* d_in, const int* in_sizes, int n_in,
                              void* d_out, int out_size, void* d_ws, size_t ws_size,
                              hipStream_t stream) {
  const float* x      = (const float*)d_in[0];
  const float* W_qkv  = (const float*)d_in[1];
  const float* b_qkv  = (const float*)d_in[2];
  const float* W_proj = (const float*)d_in[3];
  const float* b_proj = (const float*)d_in[4];
  float* out = (float*)d_out;

  const int B = 2, T = 2048, C = 1024;
  const int M = B * T;  // 4096

  char* ws = (char*)d_ws;
  u16* xb     = (u16*)(ws);                       // 8 MB
  u16* wqkvt  = (u16*)(ws + (8ull << 20));        // 6 MB
  u16* wprojt = (u16*)(ws + (14ull << 20));       // 2 MB
  u16* qfb    = (u16*)(ws + (16ull << 20));       // 8 MB (fragment-major Q)
  u16* kfb    = (u16*)(ws + (24ull << 20));       // 8 MB (fragment-major K)
  u16* vfb    = (u16*)(ws + (32ull << 20));       // 8 MB (fragment-major V)
  u16* sc     = (u16*)(ws + (40ull << 20));       // 8 MB
  u16* qkvb   = (u16*)(ws + (48ull << 20));       // 24 MB (bf16 qkv)

  cast_x_k<<<(M * C / 8 + 255) / 256, 256, 0, stream>>>(x, xb, M * C / 8);
  tcast_k<<<dim3(3 * C / 32, C / 32), 256, 0, stream>>>(W_qkv, wqkvt, C, 3 * C);
  tcast_k<<<dim3(C / 32, C / 32), 256, 0, stream>>>(W_proj, wprojt, C, C);
  gemm_bt_k<true><<<dim3(3 * C / 128, M / 128), 256, 0, stream>>>(xb, wqkvt, b_qkv, qkvb, M, 3 * C, C);
  rope_qk_k<<<(B * T * 16 * 32) / 256, 256, 0, stream>>>(qkvb, qfb, kfb);
  v_pack_k<<<dim3(B * 16, T / 64), 256, 0, stream>>>(qkvb, vfb);
  attn_k<<<2048, 64, 0, stream>>>(qfb, kfb, vfb, sc);
  gemm_bt_k<false><<<dim3(C / 128, M / 128), 256, 0, stream>>>(sc, wprojt, b_proj, out, M, C, C);
}